// Round 3
// baseline (810.294 us; speedup 1.0000x reference)
//
#include <hip/hip_runtime.h>
#include <hip/hip_bf16.h>
#include <math.h>

typedef __attribute__((ext_vector_type(8))) short bf16x8;
typedef __attribute__((ext_vector_type(4))) float f32x4;

#define BSZ   8192
#define DIM   1024
#define HIDN  1024
#define NH    8
#define HSZ   128
#define PN    1365
#define PPAD  1408

#define MFMA16(a, b, c) __builtin_amdgcn_mfma_f32_16x16x32_bf16(a, b, c, 0, 0, 0)

// async global->LDS, 16B per lane. LDS dest must be wave-uniform-base + lane*16
// (our dest = block_base + t*16 satisfies this per-wave).
__device__ __forceinline__ void gload_lds16(const void* g, void* l) {
    __builtin_amdgcn_global_load_lds(
        (const __attribute__((address_space(1))) unsigned int*)(unsigned long long)g,
        (__attribute__((address_space(3))) unsigned int*)(unsigned int)(unsigned long long)l,
        16, 0, 0);
}

__device__ __forceinline__ void split_bf16(float v, __hip_bfloat16* hi, __hip_bfloat16* lo) {
    __hip_bfloat16 h = __float2bfloat16(v);
    *hi = h;
    *lo = __float2bfloat16(v - __bfloat162float(h));
}

// ---------------------------------------------------------------------------
// Kernel 1: RMSNorm + causal conv(K=4) + SiLU  -> x_conv (fp32)
// ---------------------------------------------------------------------------
__global__ __launch_bounds__(256) void k_rms_conv(
    const float* __restrict__ x, const float* __restrict__ rms_w,
    const float* __restrict__ conv_w, const float* __restrict__ conv_b,
    float* __restrict__ x_conv)
{
    __shared__ float xn[3 + DIM];
    __shared__ float red[4];
    const int row = blockIdx.x;
    const int t = threadIdx.x;
    const float* xr = x + (size_t)row * DIM;

    float4 v = *(const float4*)(xr + t * 4);
    float ss = v.x * v.x + v.y * v.y + v.z * v.z + v.w * v.w;
    #pragma unroll
    for (int off = 32; off; off >>= 1) ss += __shfl_down(ss, off);
    if ((t & 63) == 0) red[t >> 6] = ss;
    if (t < 3) xn[t] = 0.0f;
    __syncthreads();
    float tot = red[0] + red[1] + red[2] + red[3];
    float scale = rsqrtf(tot * (1.0f / (float)DIM) + 1e-6f);

    float4 w = *(const float4*)(rms_w + t * 4);
    xn[3 + t * 4 + 0] = v.x * scale * w.x;
    xn[3 + t * 4 + 1] = v.y * scale * w.y;
    xn[3 + t * 4 + 2] = v.z * scale * w.z;
    xn[3 + t * 4 + 3] = v.w * scale * w.w;
    __syncthreads();

    const float cw0 = conv_w[0], cw1 = conv_w[1], cw2 = conv_w[2], cw3 = conv_w[3];
    const float cb = conv_b[0];
    float4 o;
    float* op = (float*)&o;
    #pragma unroll
    for (int j = 0; j < 4; ++j) {
        int l = t * 4 + j;
        float val = cb + cw0 * xn[l] + cw1 * xn[l + 1] + cw2 * xn[l + 2] + cw3 * xn[l + 3];
        op[j] = val * (1.0f / (1.0f + expf(-val)));
    }
    *(float4*)(x_conv + (size_t)row * DIM + t * 4) = o;
}

// ---------------------------------------------------------------------------
// Kernel 2: block-diag gates + sLSTM cell + GroupNorm -> states + on_hi/on_lo
// Grid (B/16, H), 256 threads. Input rows broadcast from LDS (wave-uniform
// addresses); weights stream from global (L2-resident, 4 MB total).
// ---------------------------------------------------------------------------
#define TB2 16
__global__ __launch_bounds__(256) void k_gates(
    const float* __restrict__ x, const float* __restrict__ h_prev,
    const float* __restrict__ c_prev, const float* __restrict__ n_prev,
    const float* __restrict__ m_prev, const float* __restrict__ xconv,
    const float* __restrict__ Wz, const float* __restrict__ Wzb,
    const float* __restrict__ Wi, const float* __restrict__ Wib,
    const float* __restrict__ Wf, const float* __restrict__ Wfb,
    const float* __restrict__ Wo, const float* __restrict__ Wob,
    const float* __restrict__ Rz, const float* __restrict__ Rzb,
    const float* __restrict__ Ri, const float* __restrict__ Rib,
    const float* __restrict__ Rf, const float* __restrict__ Rfb,
    const float* __restrict__ Ro, const float* __restrict__ Rob,
    const float* __restrict__ gn_w, const float* __restrict__ gn_b,
    float* __restrict__ out_h, float* __restrict__ out_c,
    float* __restrict__ out_n, float* __restrict__ out_m,
    __hip_bfloat16* __restrict__ on_hi, __hip_bfloat16* __restrict__ on_lo)
{
    __shared__ float xs[TB2][HSZ];
    __shared__ float xc[TB2][HSZ];
    __shared__ float hs[TB2][HSZ];
    __shared__ float musig[TB2][2];

    const int h = blockIdx.y;
    const int rb = blockIdx.x * TB2;
    const int t = threadIdx.x;

    for (int i = t; i < TB2 * 32; i += 256) {
        int r = i >> 5, c4 = (i & 31) * 4;
        size_t g = (size_t)(rb + r) * DIM + h * HSZ + c4;
        *(float4*)&xs[r][c4] = *(const float4*)(x + g);
        *(float4*)&xc[r][c4] = *(const float4*)(xconv + g);
        *(float4*)&hs[r][c4] = *(const float4*)(h_prev + g);
    }
    __syncthreads();

    const int e = t & 127;
    const int r2 = t >> 7;
    const int hb = h * (HSZ * HSZ) + e;
    const float *pWz = Wz + hb, *pWi = Wi + hb, *pWf = Wf + hb, *pWo = Wo + hb;
    const float *pRz = Rz + hb, *pRi = Ri + hb, *pRf = Rf + hb, *pRo = Ro + hb;

    float az[8] = {}, ai_[8] = {}, af_[8] = {}, ao_[8] = {};

    for (int d0 = 0; d0 < HSZ; d0 += 4) {
        float wz[4], wi[4], wf[4], wo[4], rz[4], ri[4], rf[4], ro[4];
        #pragma unroll
        for (int j = 0; j < 4; ++j) {
            int off = (d0 + j) * HSZ;
            wz[j] = pWz[off]; wi[j] = pWi[off]; wf[j] = pWf[off]; wo[j] = pWo[off];
            rz[j] = pRz[off]; ri[j] = pRi[off]; rf[j] = pRf[off]; ro[j] = pRo[off];
        }
        #pragma unroll
        for (int k2 = 0; k2 < 8; ++k2) {
            int r = (r2 << 3) + k2;
            float4 xv = *(const float4*)&xs[r][d0];
            float4 cv = *(const float4*)&xc[r][d0];
            float4 hv = *(const float4*)&hs[r][d0];
            float xa[4] = {xv.x, xv.y, xv.z, xv.w};
            float ca[4] = {cv.x, cv.y, cv.z, cv.w};
            float ha[4] = {hv.x, hv.y, hv.z, hv.w};
            #pragma unroll
            for (int j = 0; j < 4; ++j) {
                az[k2]  = fmaf(xa[j], wz[j], fmaf(ha[j], rz[j], az[k2]));
                ao_[k2] = fmaf(xa[j], wo[j], fmaf(ha[j], ro[j], ao_[k2]));
                ai_[k2] = fmaf(ca[j], wi[j], fmaf(ha[j], ri[j], ai_[k2]));
                af_[k2] = fmaf(ca[j], wf[j], fmaf(ha[j], rf[j], af_[k2]));
            }
        }
    }

    const int col = h * HSZ + e;
    const float bz = Wzb[col] + Rzb[col];
    const float bi = Wib[col] + Rib[col];
    const float bf = Wfb[col] + Rfb[col];
    const float bo = Wob[col] + Rob[col];

    __syncthreads();   // done reading xs/xc/hs; xs reused for h_t

    #pragma unroll
    for (int k2 = 0; k2 < 8; ++k2) {
        int r = (r2 << 3) + k2;
        size_t gi = (size_t)(rb + r) * HIDN + col;
        float cp = c_prev[gi], np = n_prev[gi], mp = m_prev[gi];
        float zg = tanhf(az[k2] + bz);
        float og = 1.0f / (1.0f + expf(-(ao_[k2] + bo)));
        float it = ai_[k2] + bi;
        float ft = af_[k2] + bf;
        float mt = fmaxf(ft + mp, it);
        float ig = expf(it - mt);
        float fg = expf(ft + mp - mt);
        float ct = fg * cp + ig * zg;
        float nt = fg * np + ig;
        float ht = og * ct / nt;
        out_m[gi] = mt; out_c[gi] = ct; out_n[gi] = nt; out_h[gi] = ht;
        xs[r][e] = ht;
    }
    __syncthreads();

    {
        const int s = t & 15, row = t >> 4;
        float sum = 0.0f, sq = 0.0f;
        #pragma unroll
        for (int j = 0; j < 8; ++j) {
            float v = xs[row][s + 16 * j];
            sum += v; sq += v * v;
        }
        #pragma unroll
        for (int off = 8; off; off >>= 1) {
            sum += __shfl_xor(sum, off);
            sq  += __shfl_xor(sq, off);
        }
        if (s == 0) {
            float mu = sum * (1.0f / 128.0f);
            float var = sq * (1.0f / 128.0f) - mu * mu;
            musig[row][0] = mu;
            musig[row][1] = rsqrtf(var + 1e-5f);
        }
    }
    __syncthreads();

    const float gw = gn_w[col], gb = gn_b[col];
    #pragma unroll
    for (int k2 = 0; k2 < 8; ++k2) {
        int r = (r2 << 3) + k2;
        float on = (xs[r][e] - musig[r][0]) * musig[r][1] * gw + gb;
        size_t o = (size_t)(rb + r) * HIDN + col;
        __hip_bfloat16 hi, lo;
        split_bf16(on, &hi, &lo);
        on_hi[o] = hi; on_lo[o] = lo;
    }
}

// ---------------------------------------------------------------------------
// Kernel 3: transpose-convert fp32 [K][N] -> bf16 hi/lo [Npad][Kpad]
// K-pad and N-pad regions zero-filled (no poison enters MFMA operands).
// grid (Kpad/32, Npad/32), 256 threads.
// ---------------------------------------------------------------------------
__global__ __launch_bounds__(256) void k_tconv(
    const float* __restrict__ src, int K, int N, int Kpad, int Npad,
    __hip_bfloat16* __restrict__ dhi, __hip_bfloat16* __restrict__ dlo)
{
    __shared__ float tile[32][33];
    const int bk = blockIdx.x * 32;
    const int bn = blockIdx.y * 32;
    const int t = threadIdx.x;
    #pragma unroll
    for (int i = 0; i < 4; ++i) {
        int idx = t + i * 256; int r = idx >> 5, c = idx & 31;
        int gk = bk + r, gn = bn + c;
        float v = 0.0f;
        if (gk < K && gn < N) v = src[(size_t)gk * N + gn];
        tile[r][c] = v;
    }
    __syncthreads();
    #pragma unroll
    for (int i = 0; i < 4; ++i) {
        int idx = t + i * 256; int r = idx >> 5, c = idx & 31;
        int gn = bn + r, gk = bk + c;
        if (gn < Npad && gk < Kpad) {
            float v = tile[c][r];   // zero when gn>=N or gk>=K
            __hip_bfloat16 hi, lo;
            split_bf16(v, &hi, &lo);
            size_t o = (size_t)gn * Kpad + gk;
            dhi[o] = hi; dlo[o] = lo;
        }
    }
}

// ---------------------------------------------------------------------------
// Kernel 4: dual up-proj GEMM (bf16x3 MFMA) + GeLU gate -> ff_hi/ff_lo
// Tile 128 rows x 64 cols (both L and R). Grid (64, 22). 4 waves, 64x32 each.
// ---------------------------------------------------------------------------
#define U_AHI 0
#define U_ALO 8192
#define U_BLH 16384
#define U_BLL 20480
#define U_BRH 24576
#define U_BRL 28672
__global__ __launch_bounds__(256, 2) void k_up(
    const __hip_bfloat16* __restrict__ on_hi, const __hip_bfloat16* __restrict__ on_lo,
    const __hip_bfloat16* __restrict__ wLhi, const __hip_bfloat16* __restrict__ wLlo,
    const __hip_bfloat16* __restrict__ wRhi, const __hip_bfloat16* __restrict__ wRlo,
    const float* __restrict__ bL, const float* __restrict__ bR,
    __hip_bfloat16* __restrict__ ff_hi, __hip_bfloat16* __restrict__ ff_lo)
{
    __shared__ __align__(16) char smem[32768];
    const int t = threadIdx.x;
    const int bm = blockIdx.x * 128;
    const int bn = blockIdx.y * 64;

    const int srow = t >> 2, sslot = (t & 3) * 8;   // 64 rows x 32 k per gload batch
    const __hip_bfloat16* pAh = on_hi + (size_t)(bm + srow) * 1024 + sslot;
    const __hip_bfloat16* pAl = on_lo + (size_t)(bm + srow) * 1024 + sslot;
    const __hip_bfloat16* pLh = wLhi + (size_t)(bn + srow) * 1024 + sslot;
    const __hip_bfloat16* pLl = wLlo + (size_t)(bn + srow) * 1024 + sslot;
    const __hip_bfloat16* pRh = wRhi + (size_t)(bn + srow) * 1024 + sslot;
    const __hip_bfloat16* pRl = wRlo + (size_t)(bn + srow) * 1024 + sslot;

    const int lane = t & 63, l15 = lane & 15, l4 = lane >> 4;
    const int wave = t >> 6;
    const int wm = (wave >> 1) * 64, wn = (wave & 1) * 32;
    const int aoff = (wm + l15) * 64 + l4 * 16;   // byte offsets, 64 B per row
    const int boff = (wn + l15) * 64 + l4 * 16;

    f32x4 accL[4][2] = {};
    f32x4 accR[4][2] = {};

    for (int k0 = 0; k0 < 1024; k0 += 32) {
        gload_lds16(pAh + k0,          smem + U_AHI + t * 16);
        gload_lds16(pAh + 65536 + k0,  smem + U_AHI + 4096 + t * 16);
        gload_lds16(pAl + k0,          smem + U_ALO + t * 16);
        gload_lds16(pAl + 65536 + k0,  smem + U_ALO + 4096 + t * 16);
        gload_lds16(pLh + k0,          smem + U_BLH + t * 16);
        gload_lds16(pLl + k0,          smem + U_BLL + t * 16);
        gload_lds16(pRh + k0,          smem + U_BRH + t * 16);
        gload_lds16(pRl + k0,          smem + U_BRL + t * 16);
        __syncthreads();

        bf16x8 ah[4], al[4];
        #pragma unroll
        for (int mr = 0; mr < 4; ++mr) {
            ah[mr] = *(const bf16x8*)(smem + U_AHI + aoff + mr * 1024);
            al[mr] = *(const bf16x8*)(smem + U_ALO + aoff + mr * 1024);
        }
        #pragma unroll
        for (int nr = 0; nr < 2; ++nr) {
            bf16x8 blh = *(const bf16x8*)(smem + U_BLH + boff + nr * 1024);
            bf16x8 bll = *(const bf16x8*)(smem + U_BLL + boff + nr * 1024);
            bf16x8 brh = *(const bf16x8*)(smem + U_BRH + boff + nr * 1024);
            bf16x8 brl = *(const bf16x8*)(smem + U_BRL + boff + nr * 1024);
            #pragma unroll
            for (int mr = 0; mr < 4; ++mr) {
                accL[mr][nr] = MFMA16(ah[mr], blh, accL[mr][nr]);
                accL[mr][nr] = MFMA16(al[mr], blh, accL[mr][nr]);
                accL[mr][nr] = MFMA16(ah[mr], bll, accL[mr][nr]);
                accR[mr][nr] = MFMA16(ah[mr], brh, accR[mr][nr]);
                accR[mr][nr] = MFMA16(al[mr], brh, accR[mr][nr]);
                accR[mr][nr] = MFMA16(ah[mr], brl, accR[mr][nr]);
            }
        }
        __syncthreads();
    }

    #pragma unroll
    for (int mr = 0; mr < 4; ++mr) {
        #pragma unroll
        for (int nr = 0; nr < 2; ++nr) {
            int n = bn + wn + nr * 16 + l15;
            bool valid = n < PN;
            float bLv = valid ? bL[n] : 0.0f;
            float bRv = valid ? bR[n] : 0.0f;
            #pragma unroll
            for (int j = 0; j < 4; ++j) {
                int row = bm + wm + mr * 16 + l4 * 4 + j;
                size_t o = (size_t)row * PPAD + n;
                float v = 0.0f;
                if (valid) {
                    float lf = accL[mr][nr][j] + bLv;
                    float rf = accR[mr][nr][j] + bRv;
                    float g = 0.5f * rf * (1.0f + erff(rf * 0.70710678f));
                    v = lf * g;
                }
                __hip_bfloat16 hi, lo;
                split_bf16(v, &hi, &lo);
                ff_hi[o] = hi; ff_lo[o] = lo;
            }
        }
    }
}

// ---------------------------------------------------------------------------
// Kernel 5: down-proj GEMM (bf16x3) + bias + residual -> out
// M=8192 N=1024 K=1408(zero-padded). Tile 128x128, grid (64, 8), 4 waves 64x64.
// ---------------------------------------------------------------------------
#define D_AHI 0
#define D_ALO 8192
#define D_BHI 16384
#define D_BLO 24576
__global__ __launch_bounds__(256, 2) void k_down(
    const __hip_bfloat16* __restrict__ ff_hi, const __hip_bfloat16* __restrict__ ff_lo,
    const __hip_bfloat16* __restrict__ dwhi, const __hip_bfloat16* __restrict__ dwlo,
    const float* __restrict__ db, const float* __restrict__ x,
    float* __restrict__ out)
{
    __shared__ __align__(16) char smem[32768];
    const int t = threadIdx.x;
    const int bm = blockIdx.x * 128;
    const int bn = blockIdx.y * 128;

    const int srow = t >> 2, sslot = (t & 3) * 8;
    const __hip_bfloat16* pAh = ff_hi + (size_t)(bm + srow) * PPAD + sslot;
    const __hip_bfloat16* pAl = ff_lo + (size_t)(bm + srow) * PPAD + sslot;
    const __hip_bfloat16* pBh = dwhi + (size_t)(bn + srow) * PPAD + sslot;
    const __hip_bfloat16* pBl = dwlo + (size_t)(bn + srow) * PPAD + sslot;
    const int rstep = 64 * PPAD;   // +64 rows

    const int lane = t & 63, l15 = lane & 15, l4 = lane >> 4;
    const int wave = t >> 6;
    const int wm = (wave >> 1) * 64, wn = (wave & 1) * 64;
    const int aoff = (wm + l15) * 64 + l4 * 16;
    const int boff = (wn + l15) * 64 + l4 * 16;

    f32x4 acc[4][4] = {};

    for (int k0 = 0; k0 < PPAD; k0 += 32) {
        gload_lds16(pAh + k0,         smem + D_AHI + t * 16);
        gload_lds16(pAh + rstep + k0, smem + D_AHI + 4096 + t * 16);
        gload_lds16(pAl + k0,         smem + D_ALO + t * 16);
        gload_lds16(pAl + rstep + k0, smem + D_ALO + 4096 + t * 16);
        gload_lds16(pBh + k0,         smem + D_BHI + t * 16);
        gload_lds16(pBh + rstep + k0, smem + D_BHI + 4096 + t * 16);
        gload_lds16(pBl + k0,         smem + D_BLO + t * 16);
        gload_lds16(pBl + rstep + k0, smem + D_BLO + 4096 + t * 16);
        __syncthreads();

        bf16x8 ah[4], al[4];
        #pragma unroll
        for (int mr = 0; mr < 4; ++mr) {
            ah[mr] = *(const bf16x8*)(smem + D_AHI + aoff + mr * 1024);
            al[mr] = *(const bf16x8*)(smem + D_ALO + aoff + mr * 1024);
        }
        #pragma unroll
        for (int nr = 0; nr < 4; ++nr) {
            bf16x8 bh = *(const bf16x8*)(smem + D_BHI + boff + nr * 1024);
            bf16x8 bl = *(const bf16x8*)(smem + D_BLO + boff + nr * 1024);
            #pragma unroll
            for (int mr = 0; mr < 4; ++mr) {
                acc[mr][nr] = MFMA16(ah[mr], bh, acc[mr][nr]);
                acc[mr][nr] = MFMA16(al[mr], bh, acc[mr][nr]);
                acc[mr][nr] = MFMA16(ah[mr], bl, acc[mr][nr]);
            }
        }
        __syncthreads();
    }

    #pragma unroll
    for (int mr = 0; mr < 4; ++mr) {
        #pragma unroll
        for (int nr = 0; nr < 4; ++nr) {
            int col = bn + wn + nr * 16 + l15;
            float dbv = db[col];
            #pragma unroll
            for (int j = 0; j < 4; ++j) {
                int row = bm + wm + mr * 16 + l4 * 4 + j;
                size_t o = (size_t)row * HIDN + col;
                out[o] = acc[mr][nr][j] + dbv + x[o];
            }
        }
    }
}

// ---------------------------------------------------------------------------
extern "C" void kernel_launch(void* const* d_in, const int* in_sizes, int n_in,
                              void* d_out, int out_size, void* d_ws, size_t ws_size,
                              hipStream_t stream) {
    const float* x      = (const float*)d_in[0];
    const float* h_prev = (const float*)d_in[1];
    const float* c_prev = (const float*)d_in[2];
    const float* n_prev = (const float*)d_in[3];
    const float* m_prev = (const float*)d_in[4];
    const float* rms_w  = (const float*)d_in[5];
    const float* conv_w = (const float*)d_in[6];
    const float* conv_b = (const float*)d_in[7];
    const float* Wz_w = (const float*)d_in[8],  *Wz_b = (const float*)d_in[9];
    const float* Wi_w = (const float*)d_in[10], *Wi_b = (const float*)d_in[11];
    const float* Wf_w = (const float*)d_in[12], *Wf_b = (const float*)d_in[13];
    const float* Wo_w = (const float*)d_in[14], *Wo_b = (const float*)d_in[15];
    const float* Rz_w = (const float*)d_in[16], *Rz_b = (const float*)d_in[17];
    const float* Ri_w = (const float*)d_in[18], *Ri_b = (const float*)d_in[19];
    const float* Rf_w = (const float*)d_in[20], *Rf_b = (const float*)d_in[21];
    const float* Ro_w = (const float*)d_in[22], *Ro_b = (const float*)d_in[23];
    const float* gn_w = (const float*)d_in[24], *gn_b = (const float*)d_in[25];
    const float* upL_w = (const float*)d_in[26], *upL_b = (const float*)d_in[27];
    const float* upR_w = (const float*)d_in[28], *upR_b = (const float*)d_in[29];
    const float* down_w = (const float*)d_in[30], *down_b = (const float*)d_in[31];

    float* out_final = (float*)d_out;
    float* out_h = out_final + (size_t)BSZ * HIDN;
    float* out_c = out_h + (size_t)BSZ * HIDN;
    float* out_n = out_c + (size_t)BSZ * HIDN;
    float* out_m = out_n + (size_t)BSZ * HIDN;
    // on_hi/on_lo park in the final-output region (exactly 32 MB), overwritten
    // only by the last kernel (k_down), which does not read them.
    __hip_bfloat16* on_hi = (__hip_bfloat16*)out_final;
    __hip_bfloat16* on_lo = on_hi + (size_t)BSZ * HIDN;

    // workspace layout (63.4 MB needed):
    //   [0,32M)        x_conv fp32          (dead after k_gates)
    //   [0,46.1M)      ff_hi, ff_lo bf16    (written by k_up, after x_conv dead)
    //   [46.1M,63.4M)  converted weights (hi/lo, transposed [n][kpad])
    const size_t NEEDED_WS = 63438848ull;
    if (ws_size < NEEDED_WS) {
        // Scratch too small: launch nothing -> harness reports incorrect output
        // (clean diagnostic) instead of OOB writes that could kill the container.
        return;
    }
    char* wsb = (char*)d_ws;
    float* x_conv = (float*)wsb;
    __hip_bfloat16* ff_hi = (__hip_bfloat16*)wsb;
    __hip_bfloat16* ff_lo = (__hip_bfloat16*)(wsb + 23068672ull);
    __hip_bfloat16* wLhi  = (__hip_bfloat16*)(wsb + 46137344ull);
    __hip_bfloat16* wLlo  = (__hip_bfloat16*)(wsb + 49020928ull);
    __hip_bfloat16* wRhi  = (__hip_bfloat16*)(wsb + 51904512ull);
    __hip_bfloat16* wRlo  = (__hip_bfloat16*)(wsb + 54788096ull);
    __hip_bfloat16* dwhi  = (__hip_bfloat16*)(wsb + 57671680ull);
    __hip_bfloat16* dwlo  = (__hip_bfloat16*)(wsb + 60555264ull);

    // weight conversions (transpose to [n][kpad], split hi/lo, pads zeroed)
    k_tconv<<<dim3(32, 44), 256, 0, stream>>>(upL_w, 1024, PN, 1024, PPAD, wLhi, wLlo);
    k_tconv<<<dim3(32, 44), 256, 0, stream>>>(upR_w, 1024, PN, 1024, PPAD, wRhi, wRlo);
    k_tconv<<<dim3(44, 32), 256, 0, stream>>>(down_w, PN, 1024, PPAD, 1024, dwhi, dwlo);

    k_rms_conv<<<dim3(BSZ), 256, 0, stream>>>(x, rms_w, conv_w, conv_b, x_conv);

    k_gates<<<dim3(BSZ / TB2, NH), 256, 0, stream>>>(
        x, h_prev, c_prev, n_prev, m_prev, x_conv,
        Wz_w, Wz_b, Wi_w, Wi_b, Wf_w, Wf_b, Wo_w, Wo_b,
        Rz_w, Rz_b, Ri_w, Ri_b, Rf_w, Rf_b, Ro_w, Ro_b,
        gn_w, gn_b, out_h, out_c, out_n, out_m, on_hi, on_lo);

    k_up<<<dim3(BSZ / 128, PPAD / 64), 256, 0, stream>>>(
        on_hi, on_lo, wLhi, wLlo, wRhi, wRlo, upL_b, upR_b, ff_hi, ff_lo);

    k_down<<<dim3(BSZ / 128, HIDN / 128), 256, 0, stream>>>(
        ff_hi, ff_lo, dwhi, dwlo, down_b, x, out_final);
}

// Round 4
// 735.480 us; speedup vs baseline: 1.1017x; 1.1017x over previous
//
#include <hip/hip_runtime.h>
#include <hip/hip_bf16.h>
#include <math.h>

typedef __attribute__((ext_vector_type(8))) short bf16x8;
typedef __attribute__((ext_vector_type(4))) float f32x4;

#define BSZ   8192
#define DIM   1024
#define HIDN  1024
#define NH    8
#define HSZ   128
#define PN    1365
#define PPAD  1408

#define MFMA16(a, b, c) __builtin_amdgcn_mfma_f32_16x16x32_bf16(a, b, c, 0, 0, 0)

// async global->LDS, 16B per lane (dest = wave-uniform base + lane*16).
__device__ __forceinline__ void gload_lds16(const void* g, void* l) {
    __builtin_amdgcn_global_load_lds(
        (const __attribute__((address_space(1))) unsigned int*)(unsigned long long)g,
        (__attribute__((address_space(3))) unsigned int*)(unsigned int)(unsigned long long)l,
        16, 0, 0);
}

__device__ __forceinline__ void split_bf16(float v, __hip_bfloat16* hi, __hip_bfloat16* lo) {
    __hip_bfloat16 h = __float2bfloat16(v);
    *hi = h;
    *lo = __float2bfloat16(v - __bfloat162float(h));
}
__device__ __forceinline__ unsigned short bf_hi(float v) {
    union { __hip_bfloat16 b; unsigned short u; } c;
    c.b = __float2bfloat16(v);
    return c.u;
}
__device__ __forceinline__ unsigned short bf_lo(float v) {
    __hip_bfloat16 h = __float2bfloat16(v);
    union { __hip_bfloat16 b; unsigned short u; } c;
    c.b = __float2bfloat16(v - __bfloat162float(h));
    return c.u;
}

// ---------------------------------------------------------------------------
// Kernel 1: RMSNorm + causal conv(K=4) + SiLU; emits bf16 hi/lo of
// x (raw), silu(conv(rms(x))), and h_prev. One block per row.
// ---------------------------------------------------------------------------
__global__ __launch_bounds__(256) void k_rms_conv(
    const float* __restrict__ x, const float* __restrict__ h_prev,
    const float* __restrict__ rms_w,
    const float* __restrict__ conv_w, const float* __restrict__ conv_b,
    unsigned short* __restrict__ xh_hi, unsigned short* __restrict__ xh_lo,
    unsigned short* __restrict__ xch_hi, unsigned short* __restrict__ xch_lo,
    unsigned short* __restrict__ hh_hi, unsigned short* __restrict__ hh_lo)
{
    __shared__ float xn[3 + DIM];
    __shared__ float red[4];
    const int row = blockIdx.x;
    const int t = threadIdx.x;
    const size_t base = (size_t)row * DIM + t * 4;

    float4 v = *(const float4*)(x + base);
    float4 hv = *(const float4*)(h_prev + base);
    float ss = v.x * v.x + v.y * v.y + v.z * v.z + v.w * v.w;
    #pragma unroll
    for (int off = 32; off; off >>= 1) ss += __shfl_down(ss, off);
    if ((t & 63) == 0) red[t >> 6] = ss;
    if (t < 3) xn[t] = 0.0f;
    __syncthreads();
    float tot = red[0] + red[1] + red[2] + red[3];
    float scale = rsqrtf(tot * (1.0f / (float)DIM) + 1e-6f);

    float4 w = *(const float4*)(rms_w + t * 4);
    xn[3 + t * 4 + 0] = v.x * scale * w.x;
    xn[3 + t * 4 + 1] = v.y * scale * w.y;
    xn[3 + t * 4 + 2] = v.z * scale * w.z;
    xn[3 + t * 4 + 3] = v.w * scale * w.w;

    // x and h_prev hi/lo (no dependence on xn)
    ushort4 ph, pl;
    ph.x = bf_hi(v.x); ph.y = bf_hi(v.y); ph.z = bf_hi(v.z); ph.w = bf_hi(v.w);
    pl.x = bf_lo(v.x); pl.y = bf_lo(v.y); pl.z = bf_lo(v.z); pl.w = bf_lo(v.w);
    *(ushort4*)(xh_hi + base) = ph;
    *(ushort4*)(xh_lo + base) = pl;
    ph.x = bf_hi(hv.x); ph.y = bf_hi(hv.y); ph.z = bf_hi(hv.z); ph.w = bf_hi(hv.w);
    pl.x = bf_lo(hv.x); pl.y = bf_lo(hv.y); pl.z = bf_lo(hv.z); pl.w = bf_lo(hv.w);
    *(ushort4*)(hh_hi + base) = ph;
    *(ushort4*)(hh_lo + base) = pl;
    __syncthreads();

    const float cw0 = conv_w[0], cw1 = conv_w[1], cw2 = conv_w[2], cw3 = conv_w[3];
    const float cb = conv_b[0];
    float o[4];
    #pragma unroll
    for (int j = 0; j < 4; ++j) {
        int l = t * 4 + j;
        float val = cb + cw0 * xn[l] + cw1 * xn[l + 1] + cw2 * xn[l + 2] + cw3 * xn[l + 3];
        o[j] = val * (1.0f / (1.0f + expf(-val)));
    }
    ph.x = bf_hi(o[0]); ph.y = bf_hi(o[1]); ph.z = bf_hi(o[2]); ph.w = bf_hi(o[3]);
    pl.x = bf_lo(o[0]); pl.y = bf_lo(o[1]); pl.z = bf_lo(o[2]); pl.w = bf_lo(o[3]);
    *(ushort4*)(xch_hi + base) = ph;
    *(ushort4*)(xch_lo + base) = pl;
}

// ---------------------------------------------------------------------------
// Kernel 2: pack gate weights into MFMA-fragment order, bf16 hi/lo.
// Layout: chunk[(hg*8 + ks)*8 + ni] of 512 els; el = lane*8 + j where lane's
// (n_local, k_local) = (lane&15, (lane>>4)*8 + j). K: 0..127 = W, 128..255 = R.
// Gate order g: 0=z, 1=o, 2=i, 3=f. grid (8 ks, 32 hg), 256 thr.
// ---------------------------------------------------------------------------
__global__ __launch_bounds__(256) void k_gw_pack(
    const float* __restrict__ Wz, const float* __restrict__ Wo,
    const float* __restrict__ Wi, const float* __restrict__ Wf,
    const float* __restrict__ Rz, const float* __restrict__ Ro,
    const float* __restrict__ Ri, const float* __restrict__ Rf,
    unsigned short* __restrict__ wgp_hi, unsigned short* __restrict__ wgp_lo)
{
    __shared__ float tile[32][129];
    const int ks = blockIdx.x;          // 0..7
    const int hg = blockIdx.y;          // 0..31
    const int h = hg >> 2, g = hg & 3;
    const float* W = (g == 0) ? Wz : (g == 1) ? Wo : (g == 2) ? Wi : Wf;
    const float* R = (g == 0) ? Rz : (g == 1) ? Ro : (g == 2) ? Ri : Rf;
    const float* src = ((ks < 4) ? W : R) + h * 16384 + ((ks & 3) * 32) * 128;
    const int t = threadIdx.x;
    #pragma unroll
    for (int i = 0; i < 16; ++i) {
        int idx = t + i * 256;
        tile[idx >> 7][idx & 127] = src[(idx >> 7) * 128 + (idx & 127)];
    }
    __syncthreads();
    const size_t obase = ((size_t)hg * 8 + ks) * 4096;
    #pragma unroll
    for (int i = 0; i < 16; ++i) {
        int oidx = t + i * 256;
        int ni = oidx >> 9, lane = (oidx >> 3) & 63, j = oidx & 7;
        int nl = lane & 15, kl = (lane >> 4) * 8 + j;
        float v = tile[kl][ni * 16 + nl];
        wgp_hi[obase + oidx] = bf_hi(v);
        wgp_lo[obase + oidx] = bf_lo(v);
    }
}

// ---------------------------------------------------------------------------
// Kernel 3: MFMA gates + sLSTM cell + GroupNorm.
// Block = 32 rows x 1 head; 4 waves = 4 gates (z,o,i,f).
// Per wave: M=32 N=128 K=256 (input||h_prev), bf16x3 split.
// Gate exchange via 2-phase LDS (z,o then i,f). Grid (256, 8).
// ---------------------------------------------------------------------------
__global__ __launch_bounds__(256, 2) void k_gates(
    const unsigned short* __restrict__ xh_hi, const unsigned short* __restrict__ xh_lo,
    const unsigned short* __restrict__ xch_hi, const unsigned short* __restrict__ xch_lo,
    const unsigned short* __restrict__ hh_hi, const unsigned short* __restrict__ hh_lo,
    const unsigned short* __restrict__ wgp_hi, const unsigned short* __restrict__ wgp_lo,
    const float* __restrict__ Wzb, const float* __restrict__ Wob,
    const float* __restrict__ Wib, const float* __restrict__ Wfb,
    const float* __restrict__ Rzb, const float* __restrict__ Rob,
    const float* __restrict__ Rib, const float* __restrict__ Rfb,
    const float* __restrict__ c_prev, const float* __restrict__ n_prev,
    const float* __restrict__ m_prev,
    const float* __restrict__ gn_w, const float* __restrict__ gn_b,
    float* __restrict__ out_h, float* __restrict__ out_c,
    float* __restrict__ out_n, float* __restrict__ out_m,
    __hip_bfloat16* __restrict__ on_hi, __hip_bfloat16* __restrict__ on_lo)
{
    __shared__ float GL[2][32][132];   // 2-phase gate exchange (pad 132 -> <=2-way)
    __shared__ float musig[32][2];

    const int t = threadIdx.x;
    const int h = blockIdx.y;
    const int rb = blockIdx.x * 32;
    const int g = t >> 6;              // wave = gate
    const int lane = t & 63, l15 = lane & 15, l4 = lane >> 4;
    const int hg = h * 4 + g;

    const unsigned short* a1h = (g < 2) ? xh_hi : xch_hi;
    const unsigned short* a1l = (g < 2) ? xh_lo : xch_lo;

    f32x4 acc[2][8] = {};
    const size_t rowA0 = (size_t)(rb + l15) * 1024 + h * 128 + l4 * 8;
    const size_t rowA1 = rowA0 + (size_t)16 * 1024;

#define GSTEP(SH, SL, KS)                                                      \
    {                                                                          \
        const int kk = ((KS) & 3) * 32;                                        \
        bf16x8 f0h = *(const bf16x8*)((SH) + rowA0 + kk);                      \
        bf16x8 f0l = *(const bf16x8*)((SL) + rowA0 + kk);                      \
        bf16x8 f1h = *(const bf16x8*)((SH) + rowA1 + kk);                      \
        bf16x8 f1l = *(const bf16x8*)((SL) + rowA1 + kk);                      \
        _Pragma("unroll")                                                      \
        for (int ni = 0; ni < 8; ++ni) {                                       \
            size_t bo = (((size_t)hg * 8 + (KS)) * 8 + ni) * 512 + lane * 8;   \
            bf16x8 bh = *(const bf16x8*)(wgp_hi + bo);                         \
            bf16x8 bl = *(const bf16x8*)(wgp_lo + bo);                         \
            acc[0][ni] = MFMA16(f0h, bh, acc[0][ni]);                          \
            acc[0][ni] = MFMA16(f0l, bh, acc[0][ni]);                          \
            acc[0][ni] = MFMA16(f0h, bl, acc[0][ni]);                          \
            acc[1][ni] = MFMA16(f1h, bh, acc[1][ni]);                          \
            acc[1][ni] = MFMA16(f1l, bh, acc[1][ni]);                          \
            acc[1][ni] = MFMA16(f1h, bl, acc[1][ni]);                          \
        }                                                                      \
    }

    GSTEP(a1h, a1l, 0) GSTEP(a1h, a1l, 1) GSTEP(a1h, a1l, 2) GSTEP(a1h, a1l, 3)
    GSTEP(hh_hi, hh_lo, 4) GSTEP(hh_hi, hh_lo, 5)
    GSTEP(hh_hi, hh_lo, 6) GSTEP(hh_hi, hh_lo, 7)
#undef GSTEP

    // ---- phase A: waves z(0), o(1) publish; D map: row=mi*16+l4*4+r, col=ni*16+l15
    if (g < 2) {
        #pragma unroll
        for (int mi = 0; mi < 2; ++mi)
            #pragma unroll
            for (int ni = 0; ni < 8; ++ni)
                #pragma unroll
                for (int r = 0; r < 4; ++r)
                    GL[g][mi * 16 + l4 * 4 + r][ni * 16 + l15] = acc[mi][ni][r];
    }
    __syncthreads();

    const int e = t & 127;
    const int r2 = t >> 7;
    const int col = h * 128 + e;
    const float bz = Wzb[col] + Rzb[col];
    const float bo_ = Wob[col] + Rob[col];
    const float bi = Wib[col] + Rib[col];
    const float bf_ = Wfb[col] + Rfb[col];

    float zg[16], og[16];
    #pragma unroll
    for (int k2 = 0; k2 < 16; ++k2) {
        int r = r2 * 16 + k2;
        zg[k2] = tanhf(GL[0][r][e] + bz);
        og[k2] = 1.0f / (1.0f + expf(-(GL[1][r][e] + bo_)));
    }
    __syncthreads();

    // ---- phase B: waves i(2), f(3) publish
    if (g >= 2) {
        #pragma unroll
        for (int mi = 0; mi < 2; ++mi)
            #pragma unroll
            for (int ni = 0; ni < 8; ++ni)
                #pragma unroll
                for (int r = 0; r < 4; ++r)
                    GL[g - 2][mi * 16 + l4 * 4 + r][ni * 16 + l15] = acc[mi][ni][r];
    }
    __syncthreads();

    float htv[16];
    #pragma unroll
    for (int k2 = 0; k2 < 16; ++k2) {
        int r = r2 * 16 + k2;
        size_t gi = (size_t)(rb + r) * HIDN + col;
        float it = GL[0][r][e] + bi;
        float ft = GL[1][r][e] + bf_;
        float cp = c_prev[gi], np = n_prev[gi], mp = m_prev[gi];
        float mt = fmaxf(ft + mp, it);
        float ig = expf(it - mt);
        float fg = expf(ft + mp - mt);
        float ct = fg * cp + ig * zg[k2];
        float nt = fg * np + ig;
        float ht = og[k2] * ct / nt;
        out_m[gi] = mt; out_c[gi] = ct; out_n[gi] = nt; out_h[gi] = ht;
        htv[k2] = ht;
    }
    __syncthreads();

    // ---- h_t into LDS for GroupNorm
    #pragma unroll
    for (int k2 = 0; k2 < 16; ++k2)
        GL[0][r2 * 16 + k2][e] = htv[k2];
    __syncthreads();

    {
        const int s = t & 7, row = t >> 3;   // 8 threads per row
        float sum = 0.0f, sq = 0.0f;
        #pragma unroll
        for (int j = 0; j < 16; ++j) {
            float v = GL[0][row][s + 8 * j];
            sum += v; sq += v * v;
        }
        sum += __shfl_xor(sum, 4); sq += __shfl_xor(sq, 4);
        sum += __shfl_xor(sum, 2); sq += __shfl_xor(sq, 2);
        sum += __shfl_xor(sum, 1); sq += __shfl_xor(sq, 1);
        if (s == 0) {
            float mu = sum * (1.0f / 128.0f);
            float var = sq * (1.0f / 128.0f) - mu * mu;
            musig[row][0] = mu;
            musig[row][1] = rsqrtf(var + 1e-5f);
        }
    }
    __syncthreads();

    const float gw = gn_w[col], gb = gn_b[col];
    #pragma unroll
    for (int k2 = 0; k2 < 16; ++k2) {
        int r = r2 * 16 + k2;
        float on = (GL[0][r][e] - musig[r][0]) * musig[r][1] * gw + gb;
        size_t o = (size_t)(rb + r) * HIDN + col;
        __hip_bfloat16 hi, lo;
        split_bf16(on, &hi, &lo);
        on_hi[o] = hi; on_lo[o] = lo;
    }
}

// ---------------------------------------------------------------------------
// Kernel 4: transpose-convert fp32 [K][N] -> bf16 hi/lo [Npad][Kpad], pads zeroed.
// ---------------------------------------------------------------------------
__global__ __launch_bounds__(256) void k_tconv(
    const float* __restrict__ src, int K, int N, int Kpad, int Npad,
    __hip_bfloat16* __restrict__ dhi, __hip_bfloat16* __restrict__ dlo)
{
    __shared__ float tile[32][33];
    const int bk = blockIdx.x * 32;
    const int bn = blockIdx.y * 32;
    const int t = threadIdx.x;
    #pragma unroll
    for (int i = 0; i < 4; ++i) {
        int idx = t + i * 256; int r = idx >> 5, c = idx & 31;
        int gk = bk + r, gn = bn + c;
        float v = 0.0f;
        if (gk < K && gn < N) v = src[(size_t)gk * N + gn];
        tile[r][c] = v;
    }
    __syncthreads();
    #pragma unroll
    for (int i = 0; i < 4; ++i) {
        int idx = t + i * 256; int r = idx >> 5, c = idx & 31;
        int gn = bn + r, gk = bk + c;
        if (gn < Npad && gk < Kpad) {
            float v = tile[c][r];
            __hip_bfloat16 hi, lo;
            split_bf16(v, &hi, &lo);
            size_t o = (size_t)gn * Kpad + gk;
            dhi[o] = hi; dlo[o] = lo;
        }
    }
}

// ---------------------------------------------------------------------------
// Kernel 5: dual up-proj GEMM (bf16x3 MFMA) + GeLU gate -> ff_hi/ff_lo
// ---------------------------------------------------------------------------
#define U_AHI 0
#define U_ALO 8192
#define U_BLH 16384
#define U_BLL 20480
#define U_BRH 24576
#define U_BRL 28672
__global__ __launch_bounds__(256, 2) void k_up(
    const __hip_bfloat16* __restrict__ on_hi, const __hip_bfloat16* __restrict__ on_lo,
    const __hip_bfloat16* __restrict__ wLhi, const __hip_bfloat16* __restrict__ wLlo,
    const __hip_bfloat16* __restrict__ wRhi, const __hip_bfloat16* __restrict__ wRlo,
    const float* __restrict__ bL, const float* __restrict__ bR,
    __hip_bfloat16* __restrict__ ff_hi, __hip_bfloat16* __restrict__ ff_lo)
{
    __shared__ __align__(16) char smem[32768];
    const int t = threadIdx.x;
    const int bm = blockIdx.x * 128;
    const int bn = blockIdx.y * 64;

    const int srow = t >> 2, sslot = (t & 3) * 8;
    const __hip_bfloat16* pAh = on_hi + (size_t)(bm + srow) * 1024 + sslot;
    const __hip_bfloat16* pAl = on_lo + (size_t)(bm + srow) * 1024 + sslot;
    const __hip_bfloat16* pLh = wLhi + (size_t)(bn + srow) * 1024 + sslot;
    const __hip_bfloat16* pLl = wLlo + (size_t)(bn + srow) * 1024 + sslot;
    const __hip_bfloat16* pRh = wRhi + (size_t)(bn + srow) * 1024 + sslot;
    const __hip_bfloat16* pRl = wRlo + (size_t)(bn + srow) * 1024 + sslot;

    const int lane = t & 63, l15 = lane & 15, l4 = lane >> 4;
    const int wave = t >> 6;
    const int wm = (wave >> 1) * 64, wn = (wave & 1) * 32;
    const int aoff = (wm + l15) * 64 + l4 * 16;
    const int boff = (wn + l15) * 64 + l4 * 16;

    f32x4 accL[4][2] = {};
    f32x4 accR[4][2] = {};

    for (int k0 = 0; k0 < 1024; k0 += 32) {
        gload_lds16(pAh + k0,          smem + U_AHI + t * 16);
        gload_lds16(pAh + 65536 + k0,  smem + U_AHI + 4096 + t * 16);
        gload_lds16(pAl + k0,          smem + U_ALO + t * 16);
        gload_lds16(pAl + 65536 + k0,  smem + U_ALO + 4096 + t * 16);
        gload_lds16(pLh + k0,          smem + U_BLH + t * 16);
        gload_lds16(pLl + k0,          smem + U_BLL + t * 16);
        gload_lds16(pRh + k0,          smem + U_BRH + t * 16);
        gload_lds16(pRl + k0,          smem + U_BRL + t * 16);
        __syncthreads();

        bf16x8 ah[4], al[4];
        #pragma unroll
        for (int mr = 0; mr < 4; ++mr) {
            ah[mr] = *(const bf16x8*)(smem + U_AHI + aoff + mr * 1024);
            al[mr] = *(const bf16x8*)(smem + U_ALO + aoff + mr * 1024);
        }
        #pragma unroll
        for (int nr = 0; nr < 2; ++nr) {
            bf16x8 blh = *(const bf16x8*)(smem + U_BLH + boff + nr * 1024);
            bf16x8 bll = *(const bf16x8*)(smem + U_BLL + boff + nr * 1024);
            bf16x8 brh = *(const bf16x8*)(smem + U_BRH + boff + nr * 1024);
            bf16x8 brl = *(const bf16x8*)(smem + U_BRL + boff + nr * 1024);
            #pragma unroll
            for (int mr = 0; mr < 4; ++mr) {
                accL[mr][nr] = MFMA16(ah[mr], blh, accL[mr][nr]);
                accL[mr][nr] = MFMA16(al[mr], blh, accL[mr][nr]);
                accL[mr][nr] = MFMA16(ah[mr], bll, accL[mr][nr]);
                accR[mr][nr] = MFMA16(ah[mr], brh, accR[mr][nr]);
                accR[mr][nr] = MFMA16(al[mr], brh, accR[mr][nr]);
                accR[mr][nr] = MFMA16(ah[mr], brl, accR[mr][nr]);
            }
        }
        __syncthreads();
    }

    #pragma unroll
    for (int mr = 0; mr < 4; ++mr) {
        #pragma unroll
        for (int nr = 0; nr < 2; ++nr) {
            int n = bn + wn + nr * 16 + l15;
            bool valid = n < PN;
            float bLv = valid ? bL[n] : 0.0f;
            float bRv = valid ? bR[n] : 0.0f;
            #pragma unroll
            for (int j = 0; j < 4; ++j) {
                int row = bm + wm + mr * 16 + l4 * 4 + j;
                size_t o = (size_t)row * PPAD + n;
                float v = 0.0f;
                if (valid) {
                    float lf = accL[mr][nr][j] + bLv;
                    float rf = accR[mr][nr][j] + bRv;
                    float gg = 0.5f * rf * (1.0f + erff(rf * 0.70710678f));
                    v = lf * gg;
                }
                __hip_bfloat16 hi, lo;
                split_bf16(v, &hi, &lo);
                ff_hi[o] = hi; ff_lo[o] = lo;
            }
        }
    }
}

// ---------------------------------------------------------------------------
// Kernel 6: down-proj GEMM (bf16x3) + bias + residual -> out
// ---------------------------------------------------------------------------
#define D_AHI 0
#define D_ALO 8192
#define D_BHI 16384
#define D_BLO 24576
__global__ __launch_bounds__(256, 2) void k_down(
    const __hip_bfloat16* __restrict__ ff_hi, const __hip_bfloat16* __restrict__ ff_lo,
    const __hip_bfloat16* __restrict__ dwhi, const __hip_bfloat16* __restrict__ dwlo,
    const float* __restrict__ db, const float* __restrict__ x,
    float* __restrict__ out)
{
    __shared__ __align__(16) char smem[32768];
    const int t = threadIdx.x;
    const int bm = blockIdx.x * 128;
    const int bn = blockIdx.y * 128;

    const int srow = t >> 2, sslot = (t & 3) * 8;
    const __hip_bfloat16* pAh = ff_hi + (size_t)(bm + srow) * PPAD + sslot;
    const __hip_bfloat16* pAl = ff_lo + (size_t)(bm + srow) * PPAD + sslot;
    const __hip_bfloat16* pBh = dwhi + (size_t)(bn + srow) * PPAD + sslot;
    const __hip_bfloat16* pBl = dwlo + (size_t)(bn + srow) * PPAD + sslot;
    const int rstep = 64 * PPAD;

    const int lane = t & 63, l15 = lane & 15, l4 = lane >> 4;
    const int wave = t >> 6;
    const int wm = (wave >> 1) * 64, wn = (wave & 1) * 64;
    const int aoff = (wm + l15) * 64 + l4 * 16;
    const int boff = (wn + l15) * 64 + l4 * 16;

    f32x4 acc[4][4] = {};

    for (int k0 = 0; k0 < PPAD; k0 += 32) {
        gload_lds16(pAh + k0,         smem + D_AHI + t * 16);
        gload_lds16(pAh + rstep + k0, smem + D_AHI + 4096 + t * 16);
        gload_lds16(pAl + k0,         smem + D_ALO + t * 16);
        gload_lds16(pAl + rstep + k0, smem + D_ALO + 4096 + t * 16);
        gload_lds16(pBh + k0,         smem + D_BHI + t * 16);
        gload_lds16(pBh + rstep + k0, smem + D_BHI + 4096 + t * 16);
        gload_lds16(pBl + k0,         smem + D_BLO + t * 16);
        gload_lds16(pBl + rstep + k0, smem + D_BLO + 4096 + t * 16);
        __syncthreads();

        bf16x8 ah[4], al[4];
        #pragma unroll
        for (int mr = 0; mr < 4; ++mr) {
            ah[mr] = *(const bf16x8*)(smem + D_AHI + aoff + mr * 1024);
            al[mr] = *(const bf16x8*)(smem + D_ALO + aoff + mr * 1024);
        }
        #pragma unroll
        for (int nr = 0; nr < 4; ++nr) {
            bf16x8 bh = *(const bf16x8*)(smem + D_BHI + boff + nr * 1024);
            bf16x8 bl = *(const bf16x8*)(smem + D_BLO + boff + nr * 1024);
            #pragma unroll
            for (int mr = 0; mr < 4; ++mr) {
                acc[mr][nr] = MFMA16(ah[mr], bh, acc[mr][nr]);
                acc[mr][nr] = MFMA16(al[mr], bh, acc[mr][nr]);
                acc[mr][nr] = MFMA16(ah[mr], bl, acc[mr][nr]);
            }
        }
        __syncthreads();
    }

    #pragma unroll
    for (int mr = 0; mr < 4; ++mr) {
        #pragma unroll
        for (int nr = 0; nr < 4; ++nr) {
            int colc = bn + wn + nr * 16 + l15;
            float dbv = db[colc];
            #pragma unroll
            for (int j = 0; j < 4; ++j) {
                int row = bm + wm + mr * 16 + l4 * 4 + j;
                size_t o = (size_t)row * HIDN + colc;
                out[o] = acc[mr][nr][j] + dbv + x[o];
            }
        }
    }
}

// ---------------------------------------------------------------------------
// workspace offsets (bytes)
#define WS_XH_HI   0ull
#define WS_XH_LO   16777216ull
#define WS_XCH_HI  33554432ull
#define WS_XCH_LO  50331648ull
#define WS_HH_HI   67108864ull
#define WS_HH_LO   83886080ull
#define WS_WGP_HI  100663296ull
#define WS_WGP_LO  102760448ull
#define WS_WL_HI   104857600ull
#define WS_WL_LO   107741184ull
#define WS_WR_HI   110624768ull
#define WS_WR_LO   113508352ull
#define WS_DW_HI   116391936ull
#define WS_DW_LO   119275520ull
#define WS_END     122159104ull
#define WS_FF_HI   0ull
#define WS_FF_LO   23068672ull

extern "C" void kernel_launch(void* const* d_in, const int* in_sizes, int n_in,
                              void* d_out, int out_size, void* d_ws, size_t ws_size,
                              hipStream_t stream) {
    const float* x      = (const float*)d_in[0];
    const float* h_prev = (const float*)d_in[1];
    const float* c_prev = (const float*)d_in[2];
    const float* n_prev = (const float*)d_in[3];
    const float* m_prev = (const float*)d_in[4];
    const float* rms_w  = (const float*)d_in[5];
    const float* conv_w = (const float*)d_in[6];
    const float* conv_b = (const float*)d_in[7];
    const float* Wz_w = (const float*)d_in[8],  *Wz_b = (const float*)d_in[9];
    const float* Wi_w = (const float*)d_in[10], *Wi_b = (const float*)d_in[11];
    const float* Wf_w = (const float*)d_in[12], *Wf_b = (const float*)d_in[13];
    const float* Wo_w = (const float*)d_in[14], *Wo_b = (const float*)d_in[15];
    const float* Rz_w = (const float*)d_in[16], *Rz_b = (const float*)d_in[17];
    const float* Ri_w = (const float*)d_in[18], *Ri_b = (const float*)d_in[19];
    const float* Rf_w = (const float*)d_in[20], *Rf_b = (const float*)d_in[21];
    const float* Ro_w = (const float*)d_in[22], *Ro_b = (const float*)d_in[23];
    const float* gn_w = (const float*)d_in[24], *gn_b = (const float*)d_in[25];
    const float* upL_w = (const float*)d_in[26], *upL_b = (const float*)d_in[27];
    const float* upR_w = (const float*)d_in[28], *upR_b = (const float*)d_in[29];
    const float* down_w = (const float*)d_in[30], *down_b = (const float*)d_in[31];

    float* out_final = (float*)d_out;
    float* out_h = out_final + (size_t)BSZ * HIDN;
    float* out_c = out_h + (size_t)BSZ * HIDN;
    float* out_n = out_c + (size_t)BSZ * HIDN;
    float* out_m = out_n + (size_t)BSZ * HIDN;
    // on_hi/on_lo park in final-output region (32 MB), overwritten last by k_down.
    __hip_bfloat16* on_hi = (__hip_bfloat16*)out_final;
    __hip_bfloat16* on_lo = on_hi + (size_t)BSZ * HIDN;

    if (ws_size < WS_END) return;   // clean failure instead of OOB writes

    char* wsb = (char*)d_ws;
    unsigned short* xh_hi  = (unsigned short*)(wsb + WS_XH_HI);
    unsigned short* xh_lo  = (unsigned short*)(wsb + WS_XH_LO);
    unsigned short* xch_hi = (unsigned short*)(wsb + WS_XCH_HI);
    unsigned short* xch_lo = (unsigned short*)(wsb + WS_XCH_LO);
    unsigned short* hh_hi  = (unsigned short*)(wsb + WS_HH_HI);
    unsigned short* hh_lo  = (unsigned short*)(wsb + WS_HH_LO);
    unsigned short* wgp_hi = (unsigned short*)(wsb + WS_WGP_HI);
    unsigned short* wgp_lo = (unsigned short*)(wsb + WS_WGP_LO);
    __hip_bfloat16* wLhi   = (__hip_bfloat16*)(wsb + WS_WL_HI);
    __hip_bfloat16* wLlo   = (__hip_bfloat16*)(wsb + WS_WL_LO);
    __hip_bfloat16* wRhi   = (__hip_bfloat16*)(wsb + WS_WR_HI);
    __hip_bfloat16* wRlo   = (__hip_bfloat16*)(wsb + WS_WR_LO);
    __hip_bfloat16* dwhi   = (__hip_bfloat16*)(wsb + WS_DW_HI);
    __hip_bfloat16* dwlo   = (__hip_bfloat16*)(wsb + WS_DW_LO);
    // ff aliases the (dead after k_gates) xh/xch region
    __hip_bfloat16* ff_hi  = (__hip_bfloat16*)(wsb + WS_FF_HI);
    __hip_bfloat16* ff_lo  = (__hip_bfloat16*)(wsb + WS_FF_LO);

    k_gw_pack<<<dim3(8, 32), 256, 0, stream>>>(
        Wz_w, Wo_w, Wi_w, Wf_w, Rz_w, Ro_w, Ri_w, Rf_w, wgp_hi, wgp_lo);

    k_tconv<<<dim3(32, 44), 256, 0, stream>>>(upL_w, 1024, PN, 1024, PPAD, wLhi, wLlo);
    k_tconv<<<dim3(32, 44), 256, 0, stream>>>(upR_w, 1024, PN, 1024, PPAD, wRhi, wRlo);
    k_tconv<<<dim3(44, 32), 256, 0, stream>>>(down_w, PN, 1024, PPAD, 1024, dwhi, dwlo);

    k_rms_conv<<<dim3(BSZ), 256, 0, stream>>>(
        x, h_prev, rms_w, conv_w, conv_b,
        xh_hi, xh_lo, xch_hi, xch_lo, hh_hi, hh_lo);

    k_gates<<<dim3(BSZ / 32, NH), 256, 0, stream>>>(
        xh_hi, xh_lo, xch_hi, xch_lo, hh_hi, hh_lo, wgp_hi, wgp_lo,
        Wz_b, Wo_b, Wi_b, Wf_b, Rz_b, Ro_b, Ri_b, Rf_b,
        c_prev, n_prev, m_prev, gn_w, gn_b,
        out_h, out_c, out_n, out_m, on_hi, on_lo);

    k_up<<<dim3(BSZ / 128, PPAD / 64), 256, 0, stream>>>(
        on_hi, on_lo, wLhi, wLlo, wRhi, wRlo, upL_b, upR_b, ff_hi, ff_lo);

    k_down<<<dim3(BSZ / 128, HIDN / 128), 256, 0, stream>>>(
        ff_hi, ff_lo, dwhi, dwlo, down_b, x, out_final);
}